// Round 2
// baseline (130.085 us; speedup 1.0000x reference)
//
#include <hip/hip_runtime.h>

using bf16x8 = __attribute__((ext_vector_type(8))) short;
using f32x4  = __attribute__((ext_vector_type(4))) float;
typedef unsigned short u16;
typedef __attribute__((ext_vector_type(8))) unsigned short u16x8;
typedef __attribute__((ext_vector_type(4))) unsigned short u16x4;

__device__ __forceinline__ u16 f2b(float f){
  unsigned int i=__float_as_uint(f);
  return (u16)((i + 0x7FFFu + ((i>>16)&1u))>>16);
}
__device__ __forceinline__ float b2f(u16 u){
  union{unsigned int i; float f;}v; v.i=((unsigned int)u)<<16; return v.f;
}
__device__ __forceinline__ void async16(const void* g, void* l){
  __builtin_amdgcn_global_load_lds((__attribute__((address_space(1))) void*)(g),
                                   (__attribute__((address_space(3))) void*)(l), 16, 0, 0);
}
__device__ __forceinline__ float gelu_tanh(float v){
  float u = v*(0.7978845608f + 0.0356774081f*v*v);
  float e = __expf(-2.0f*fabsf(u));
  float th = (1.0f-e)/(1.0f+e);
  th = (u<0.f)? -th : th;
  return 0.5f*v*(1.0f+th);
}

#define BARX() do{ __asm__ volatile("" ::: "memory"); \
                   __builtin_amdgcn_s_barrier(); \
                   __asm__ volatile("" ::: "memory"); }while(0)
#define WAITV(n) __asm__ volatile("s_waitcnt vmcnt(" #n ")" ::: "memory")
#define WAITL()  __asm__ volatile("s_waitcnt lgkmcnt(0)" ::: "memory")

// Weight LDS image: per 128x128 chunk, flat u16 index = (c*128 + n)*8 + e
//   n = output col within chunk, c = k-octet (k = c*8+e)

// aout layout: per 32-token tile, c-major chunks:
//   u16 index = ((tok>>5)*16 + (ch>>3))*256 + (tok&31)*8 + (ch&7)

// ---------- K2 v3: LN1 + ALL THREE QKV chunk GEMMs, in-block weight convert ----------
// grid 392, 256 threads. No prep dependency: fp32 wqkv -> bf16 LDS image in-block,
// double-buffered (B0/B1), loads for chunk n+1 in flight across raw barriers.
__global__ __launch_bounds__(256)
void qkv_ln_kernel(const float* __restrict__ x,
                   const float* __restrict__ ln1w, const float* __restrict__ ln1b,
                   const float* __restrict__ wqkv, const float* __restrict__ bqkv,
                   u16* __restrict__ qb, u16* __restrict__ kb, u16* __restrict__ vb)
{
  __shared__ __align__(16) char smem[73728];
  char* lA = smem;            // 32x128 bf16 c-major chunks (8 KB)
  char* B0 = smem + 8192;     // 128x128 bf16 image (32 KB)
  char* B1 = smem + 40960;    // 128x128 bf16 image (32 KB)

  const int tid = threadIdx.x;
  const int lane = tid&63, wid = tid>>6;
  const int quad = lane>>4, lrow = lane&15;
  const int m0 = blockIdx.x*32;
  const int wm = (wid&1)*16, wn = (wid>>1)*64;

  // staging units: u = tid + uu*256 -> c = u>>5 (k-octet), n0 = (u&31)*4 (col quad)
  const int c0u = tid>>5, c1u = (tid>>5)+8;
  const int n0u = (tid&31)*4;

  // ---- x loads first (oldest vmem; LN waits only on these) ----
  const int row8 = tid>>3, g = tid&7;
  float4 xl[4];
  {
    const float4* xr = (const float4*)(x + (size_t)(m0+row8)*128 + g*16);
    #pragma unroll
    for (int c4=0;c4<4;c4++) xl[c4] = xr[c4];
  }

  float4 wreg[2][8];
  #define WISSUE(ncc) do{ \
    const float* wp0 = wqkv + (size_t)(ncc)*128 + (size_t)c0u*8*384 + n0u; \
    const float* wp1 = wqkv + (size_t)(ncc)*128 + (size_t)c1u*8*384 + n0u; \
    _Pragma("unroll") \
    for (int e=0;e<8;e++){ wreg[0][e] = *(const float4*)(wp0 + e*384); \
                           wreg[1][e] = *(const float4*)(wp1 + e*384); } }while(0)

  #define WCONV(Bp) do{ \
    _Pragma("unroll") \
    for (int uu=0;uu<2;uu++){ \
      int base = ((uu? c1u : c0u)*128 + n0u); \
      _Pragma("unroll") \
      for (int d=0;d<4;d++){ \
        u16x8 pk; \
        _Pragma("unroll") \
        for (int e=0;e<8;e++){ float4 t = wreg[uu][e]; \
          pk[e] = f2b(d==0? t.x : d==1? t.y : d==2? t.z : t.w); } \
        *(u16x8*)((Bp) + ((base+d)<<4)) = pk; } } }while(0)

  WISSUE(0);

  // ---- LN1 in registers: thread = (row=tid>>3, g=tid&7), 16 channels ----
  {
    float xv[16];
    float s=0.f, sq=0.f;
    #pragma unroll
    for (int c4=0;c4<4;c4++){
      float4 t = xl[c4];
      xv[c4*4]=t.x; xv[c4*4+1]=t.y; xv[c4*4+2]=t.z; xv[c4*4+3]=t.w;
      s += t.x+t.y+t.z+t.w;
      sq += t.x*t.x+t.y*t.y+t.z*t.z+t.w*t.w;
    }
    s  += __shfl_xor(s,1);  s  += __shfl_xor(s,2);  s  += __shfl_xor(s,4);
    sq += __shfl_xor(sq,1); sq += __shfl_xor(sq,2); sq += __shfl_xor(sq,4);
    float mean = s*0.0078125f;
    float rstd = rsqrtf(sq*0.0078125f - mean*mean + 1e-5f);
    const float4* wr = (const float4*)(ln1w + g*16);
    const float4* br = (const float4*)(ln1b + g*16);
    u16 nv[16];
    #pragma unroll
    for (int c4=0;c4<4;c4++){
      float4 w4 = wr[c4], b4 = br[c4];
      nv[c4*4]   = f2b((xv[c4*4]  -mean)*rstd*w4.x + b4.x);
      nv[c4*4+1] = f2b((xv[c4*4+1]-mean)*rstd*w4.y + b4.y);
      nv[c4*4+2] = f2b((xv[c4*4+2]-mean)*rstd*w4.z + b4.z);
      nv[c4*4+3] = f2b((xv[c4*4+3]-mean)*rstd*w4.w + b4.w);
    }
    #pragma unroll
    for (int cc=0;cc<2;cc++){
      u16x8 pk;
      #pragma unroll
      for (int e=0;e<8;e++) pk[e] = nv[cc*8+e];
      *(u16x8*)(lA + (((g*2+cc)*32 + row8)<<4)) = pk;
    }
  }

  WCONV(B0);      // compiler waits chunk-0 wregs here
  WISSUE(1);      // chunk-1 loads in flight across the barrier
  WAITL(); BARX();

  f32x4 acc[4];
  #define MFMAPH(Bp) do{ \
    _Pragma("unroll") for (int j=0;j<4;j++){ f32x4 z={0.f,0.f,0.f,0.f}; acc[j]=z; } \
    _Pragma("unroll") \
    for (int ks=0;ks<4;ks++){ \
      bf16x8 af = ((const bf16x8*)lA)[(ks*4+quad)*32 + wm + lrow]; \
      _Pragma("unroll") \
      for (int j=0;j<4;j++){ \
        bf16x8 bfr = ((const bf16x8*)(Bp))[(ks*4+quad)*128 + wn + j*16 + lrow]; \
        acc[j] = __builtin_amdgcn_mfma_f32_16x16x32_bf16(af, bfr, acc[j], 0,0,0); } } }while(0)

  #define QSTORE(ncc, dstp, doscale) do{ \
    _Pragma("unroll") \
    for (int j=0;j<4;j++){ \
      int col = wn + j*16 + lrow; \
      float bia = bqkv[(ncc)*128 + col]; \
      _Pragma("unroll") \
      for (int r=0;r<4;r++){ \
        int row = m0 + wm + quad*4 + r; \
        float val = acc[j][r] + bia; \
        if (doscale) val *= 0.17677669529663687f; \
        (dstp)[(size_t)row*128 + col] = f2b(val); } } }while(0)

  MFMAPH(B0); QSTORE(0, qb, 1);
  WCONV(B1);
  WISSUE(2);
  WAITL(); BARX();

  MFMAPH(B1); QSTORE(1, kb, 0);
  WCONV(B0);       // safe: all waves passed prev barrier after finishing MFMA on B0
  WAITL(); BARX();

  MFMAPH(B0); QSTORE(2, vb, 0);
}

// ---------- K3: MFMA neighborhood attention (+ folded weight conversion) ----------
#define KT_S 40
#define VT_S 232
#define P_S  152
__global__ __launch_bounds__(256)
void attn_kernel(const u16* __restrict__ qb, const u16* __restrict__ kb,
                 const u16* __restrict__ vb, const float* __restrict__ rpb,
                 const float* __restrict__ wproj, const float* __restrict__ wfc1,
                 const float* __restrict__ wfc2,
                 u16* __restrict__ tproj, u16* __restrict__ tfc1, u16* __restrict__ tfc2,
                 u16* __restrict__ aout)
{
  __shared__ __align__(16) char smem[50192];
  u16*  kt   = (u16*)smem;
  u16*  vt   = (u16*)(smem + 15680);
  u16*  Pm   = (u16*)(smem + 30528);
  float* srpb= (float*)(smem + 49984);

  const int tid = threadIdx.x;
  const int tile = blockIdx.x, bh = blockIdx.y;
  const int b = bh>>2, h = bh&3;
  const int ty = (tile/7)*8, tx = (tile%7)*8;
  const int lane = tid&63, wid = tid>>6;
  const int quad = lane>>4, lrow = lane&15;

  // ---- folded prep: fp32 mlp weights -> bf16 swizzled images (147456 u16 total) ----
  {
    int bid = bh*49 + tile;            // 0..783
    if (bid < 576){
      int Wd = bid*256 + tid;          // 0..147455, exact cover
      float v; u16* dst;
      if (Wd < 16384){
        int i=Wd>>3, e=Wd&7, n=i&127, c=i>>7;
        v = wproj[(c*8+e)*128 + n]; dst = tproj + Wd;
      } else if (Wd < 81920){
        int t = Wd - 16384; int ncc=t>>14, r=t&16383, i=r>>3, e=r&7, n=i&127, c=i>>7;
        v = wfc1[(c*8+e)*512 + ncc*128 + n]; dst = tfc1 + t;
      } else {
        int t = Wd - 81920; int ncc=t>>14, r=t&16383, i=r>>3, e=r&7, n=i&127, c=i>>7;
        v = wfc2[(ncc*128 + c*8 + e)*128 + n]; dst = tfc2 + t;
      }
      *dst = f2b(v);
    }
  }

  #pragma unroll
  for (int kk=0;kk<4;kk++){
    int i = tid + kk*256;
    if (i < 784){
      int pos = i>>2, oct = i&3;
      int hy = pos/14, hx = pos - hy*14;
      int gy = ty + hy - 3, gx = tx + hx - 3;
      u16x8 kv = {0,0,0,0,0,0,0,0};
      if (gy>=0 && gy<56 && gx>=0 && gx<56)
        kv = *(const u16x8*)(kb + ((size_t)(b*3136 + gy*56 + gx)*128 + h*32 + oct*8));
      *(u16x8*)(kt + pos*KT_S + oct*8) = kv;
    }
  }
  #pragma unroll
  for (int kk=0;kk<4;kk++){
    int i = tid + kk*256;
    if (i < 896){
      int pos = i>>2, oct = i&3;
      u16x8 vv = {0,0,0,0,0,0,0,0};
      if (pos < 196){
        int hy = pos/14, hx = pos - hy*14;
        int gy = ty + hy - 3, gx = tx + hx - 3;
        if (gy>=0 && gy<56 && gx>=0 && gx<56)
          vv = *(const u16x8*)(vb + ((size_t)(b*3136 + gy*56 + gx)*128 + h*32 + oct*8));
      }
      #pragma unroll
      for (int j=0;j<8;j++) vt[(oct*8+j)*VT_S + pos] = vv[j];
    }
  }
  if (tid < 49) srpb[tid] = rpb[h*49 + tid];
  __syncthreads();

  const int pxq = wid*16 + lrow;
  const int tokq = b*3136 + (ty + (pxq>>3))*56 + tx + (pxq&7);
  bf16x8 qf = *(const bf16x8*)(qb + (size_t)tokq*128 + h*32 + quad*8);

  f32x4 sc[7];
  const f32x4 zf = {0.f,0.f,0.f,0.f};
  #pragma unroll
  for (int cg=0;cg<7;cg++){
    int pos = wid*28 + cg*16 + lrow;
    bf16x8 kf = *(const bf16x8*)(kt + pos*KT_S + quad*8);
    sc[cg] = __builtin_amdgcn_mfma_f32_16x16x32_bf16(qf, kf, zf, 0,0,0);
  }

  const int lyq = quad>>1;
  #pragma unroll
  for (int cg=0;cg<7;cg++){
    int np = cg*16 + lrow;
    int nh = np/14, hx = np - nh*14;
    int dy = nh - lyq;
    #pragma unroll
    for (int r=0;r<4;r++){
      int lx = (quad*4+r)&7;
      int dx = hx - lx;
      bool in = ((unsigned)dy<7u) && ((unsigned)dx<7u);
      float bias = srpb[in ? (dy*7+dx) : 0];
      sc[cg][r] = in ? (sc[cg][r] + bias) : -1e30f;
    }
  }
  float inv[4];
  #pragma unroll
  for (int r=0;r<4;r++){
    float m = sc[0][r];
    #pragma unroll
    for (int cg=1;cg<7;cg++) m = fmaxf(m, sc[cg][r]);
    m = fmaxf(m, __shfl_xor(m,1)); m = fmaxf(m, __shfl_xor(m,2));
    m = fmaxf(m, __shfl_xor(m,4)); m = fmaxf(m, __shfl_xor(m,8));
    float l = 0.f;
    #pragma unroll
    for (int cg=0;cg<7;cg++){ float p = __expf(sc[cg][r]-m); sc[cg][r]=p; l+=p; }
    l += __shfl_xor(l,1); l += __shfl_xor(l,2);
    l += __shfl_xor(l,4); l += __shfl_xor(l,8);
    inv[r]=1.f/l;
  }

  u16* Pw = Pm + wid*16*P_S;
  #pragma unroll
  for (int cg=0;cg<7;cg++){
    int np = cg*16 + lrow;
    #pragma unroll
    for (int r=0;r<4;r++)
      Pw[(quad*4+r)*P_S + np] = f2b(sc[cg][r]);
  }
  { int zr = lane>>2, seg = lane&3;
    u16x4 z4 = {0,0,0,0};
    *(u16x4*)(Pw + zr*P_S + 112 + seg*4) = z4; }
  __syncthreads();

  f32x4 oacc[2] = {zf, zf};
  #pragma unroll
  for (int ks=0;ks<4;ks++){
    bf16x8 pf = *(const bf16x8*)(Pw + lrow*P_S + ks*32 + quad*8);
    #pragma unroll
    for (int cg2=0;cg2<2;cg2++){
      bf16x8 vf = *(const bf16x8*)(vt + (cg2*16+lrow)*VT_S + wid*28 + ks*32 + quad*8);
      oacc[cg2] = __builtin_amdgcn_mfma_f32_16x16x32_bf16(pf, vf, oacc[cg2], 0,0,0);
    }
  }
  #pragma unroll
  for (int r=0;r<4;r++){
    int px = wid*16 + quad*4 + r;
    int tok = b*3136 + (ty + (px>>3))*56 + tx + (px&7);
    #pragma unroll
    for (int cg2=0;cg2<2;cg2++){
      int ch = h*32 + cg2*16 + lrow;
      aout[(size_t)((tok>>5)*16 + (ch>>3))*256 + (tok&31)*8 + (ch&7)]
        = f2b(oacc[cg2][r]*inv[r]);
    }
  }
}

// ---------- K4 v2: PROJ + residual + LN2 + FC1 + GELU + FC2 + residual ----------
// M=64 tokens/block (grid 196), 512 threads / 8 waves, 3-buffer counted-vmcnt
// weight pipeline; never vmcnt(0) in the steady loop.
__device__ __forceinline__ void stage32k(const u16* __restrict__ src, char* dst, int tid){
  #pragma unroll
  for (int kk=0;kk<4;kk++){ int i = tid + kk*512; async16(src + (size_t)i*8, dst + i*16); }
}

__device__ __forceinline__ void mfma16(const char* Ab, const char* Bb,
                                       int quad, int lrow, int wm, int wn, f32x4 acc[4]){
  const int row = wm + lrow;
  #pragma unroll
  for (int ks=0;ks<4;ks++){
    bf16x8 af = ((const bf16x8*)Ab)[(row>>5)*512 + (ks*4+quad)*32 + (row&31)];
    #pragma unroll
    for (int j=0;j<4;j++){
      bf16x8 bfr = ((const bf16x8*)Bb)[(ks*4+quad)*128 + wn + j*16 + lrow];
      acc[j] = __builtin_amdgcn_mfma_f32_16x16x32_bf16(af, bfr, acc[j], 0,0,0);
    }
  }
}

__device__ __forceinline__ void fc1_phase(const char* xn2, const char* B, char* lA,
                                          const float* __restrict__ bfc1c,
                                          int quad, int lrow, int wm, int wn){
  f32x4 a2[4] = {};
  __builtin_amdgcn_s_setprio(1);
  mfma16(xn2, B, quad, lrow, wm, wn, a2);
  __builtin_amdgcn_s_setprio(0);
  #pragma unroll
  for (int j=0;j<4;j++){
    int col = wn + j*16 + lrow;
    float bia = bfc1c[col];
    #pragma unroll
    for (int r=0;r<4;r++){
      int row = wm + quad*4 + r;
      float g = gelu_tanh(a2[j][r] + bia);
      ((u16*)lA)[(row>>5)*4096 + ((col>>3)*32 + (row&31))*8 + (col&7)] = f2b(g);
    }
  }
}

__global__ __launch_bounds__(512)
void mega_mlp_kernel(const u16* __restrict__ aout, const float* __restrict__ x,
                     const u16* __restrict__ tproj, const float* __restrict__ bproj,
                     const float* __restrict__ ln2w, const float* __restrict__ ln2b,
                     const u16* __restrict__ tfc1, const float* __restrict__ bfc1,
                     const u16* __restrict__ tfc2, const float* __restrict__ bfc2,
                     float* __restrict__ out)
{
  __shared__ __align__(16) char smem[131072];
  char* B0  = smem;
  char* B1  = smem + 32768;
  char* B2  = smem + 65536;
  char* lA  = smem + 98304;
  char* xn2 = smem + 114688;
  float* redS = (float*)lA;
  float* redQ = redS + 128;

  const int tid = threadIdx.x;
  const int lane = tid&63, wid = tid>>6;
  const int quad = lane>>4, lrow = lane&15;
  const int m0 = blockIdx.x*64;
  const int wm = (wid&3)*16, wn = (wid>>2)*64;
  const int half = wid>>2;

  float xv[4][4];
  #pragma unroll
  for (int j=0;j<4;j++){
    #pragma unroll
    for (int r=0;r<4;r++)
      xv[j][r] = x[(size_t)(m0+wm+quad*4+r)*128 + wn + j*16 + lrow];
  }

  stage32k(tproj, B0, tid);
  #pragma unroll
  for (int kk=0;kk<2;kk++){
    int i = tid + kk*512;
    async16(aout + (size_t)blockIdx.x*8192 + i*8, lA + i*16);
  }
  stage32k(tfc1,           B1, tid);
  stage32k(tfc2,           B2, tid);
  WAITV(8); BARX();

  f32x4 acc[4] = {};
  __builtin_amdgcn_s_setprio(1);
  mfma16(lA, B0, quad, lrow, wm, wn, acc);
  __builtin_amdgcn_s_setprio(0);
  float x1v[4][4]; float ps[4]={0,0,0,0}, pq[4]={0,0,0,0};
  #pragma unroll
  for (int j=0;j<4;j++){
    float bia = bproj[wn + j*16 + lrow];
    #pragma unroll
    for (int r=0;r<4;r++){
      float val = acc[j][r] + bia + xv[j][r];
      x1v[j][r] = val; ps[r]+=val; pq[r]+=val*val;
    }
  }
  #pragma unroll
  for (int r=0;r<4;r++){
    #pragma unroll
    for (int off=1; off<16; off<<=1){
      ps[r]+=__shfl_xor(ps[r],off); pq[r]+=__shfl_xor(pq[r],off);
    }
  }
  BARX();
  stage32k(tfc1 + 16384,   B0, tid);
  if (lrow==0){
    #pragma unroll
    for (int r=0;r<4;r++){
      int row = wm + quad*4 + r;
      redS[half*64+row]=ps[r]; redQ[half*64+row]=pq[r];
    }
  }
  WAITL(); WAITV(8); BARX();

  {
    float w2[4], b2[4];
    #pragma unroll
    for (int j=0;j<4;j++){ int col=wn+j*16+lrow; w2[j]=ln2w[col]; b2[j]=ln2b[col]; }
    #pragma unroll
    for (int r=0;r<4;r++){
      int row = wm + quad*4 + r;
      float mean = (redS[row]+redS[64+row])*0.0078125f;
      float var  = (redQ[row]+redQ[64+row])*0.0078125f - mean*mean;
      float rstd = rsqrtf(var + 1e-5f);
      #pragma unroll
      for (int j=0;j<4;j++){
        int col = wn + j*16 + lrow;
        ((u16*)xn2)[(row>>5)*4096 + ((col>>3)*32 + (row&31))*8 + (col&7)]
          = f2b((x1v[j][r]-mean)*rstd*w2[j] + b2[j]);
      }
    }
  }
  WAITL(); BARX();

  f32x4 acc3[4] = {};

  fc1_phase(xn2, B1, lA, bfc1, quad, lrow, wm, wn);
  WAITL(); BARX();
  stage32k(tfc2 + 16384,   B1, tid);
  WAITV(8); BARX();

  __builtin_amdgcn_s_setprio(1);
  mfma16(lA, B2, quad, lrow, wm, wn, acc3);
  __builtin_amdgcn_s_setprio(0);
  BARX();
  stage32k(tfc1 + 2*16384, B2, tid);
  WAITV(8); BARX();

  fc1_phase(xn2, B0, lA, bfc1 + 128, quad, lrow, wm, wn);
  WAITL(); BARX();
  stage32k(tfc2 + 2*16384, B0, tid);
  WAITV(8); BARX();

  __builtin_amdgcn_s_setprio(1);
  mfma16(lA, B1, quad, lrow, wm, wn, acc3);
  __builtin_amdgcn_s_setprio(0);
  BARX();
  stage32k(tfc1 + 3*16384, B1, tid);
  WAITV(8); BARX();

  fc1_phase(xn2, B2, lA, bfc1 + 256, quad, lrow, wm, wn);
  WAITL(); BARX();
  stage32k(tfc2 + 3*16384, B2, tid);
  WAITV(8); BARX();

  __builtin_amdgcn_s_setprio(1);
  mfma16(lA, B0, quad, lrow, wm, wn, acc3);
  __builtin_amdgcn_s_setprio(0);
  WAITV(4); BARX();

  fc1_phase(xn2, B1, lA, bfc1 + 384, quad, lrow, wm, wn);
  WAITL(); WAITV(0); BARX();

  __builtin_amdgcn_s_setprio(1);
  mfma16(lA, B2, quad, lrow, wm, wn, acc3);
  __builtin_amdgcn_s_setprio(0);

  #pragma unroll
  for (int j=0;j<4;j++){
    int col = wn + j*16 + lrow;
    float bia = bfc2[col];
    #pragma unroll
    for (int r=0;r<4;r++){
      int row = m0 + wm + quad*4 + r;
      out[(size_t)row*128 + col] = acc3[j][r] + bia + x1v[j][r];
    }
  }
}

extern "C" void kernel_launch(void* const* d_in, const int* in_sizes, int n_in,
                              void* d_out, int out_size, void* d_ws, size_t ws_size,
                              hipStream_t stream)
{
  const float* x     =(const float*)d_in[0];
  const float* ln1w  =(const float*)d_in[1];
  const float* ln1b  =(const float*)d_in[2];
  const float* wqkv  =(const float*)d_in[3];
  const float* bqkv  =(const float*)d_in[4];
  const float* rpb   =(const float*)d_in[5];
  const float* wproj =(const float*)d_in[6];
  const float* bproj =(const float*)d_in[7];
  const float* ln2w  =(const float*)d_in[8];
  const float* ln2b  =(const float*)d_in[9];
  const float* wfc1  =(const float*)d_in[10];
  const float* bfc1  =(const float*)d_in[11];
  const float* wfc2  =(const float*)d_in[12];
  const float* bfc2  =(const float*)d_in[13];

  char* ws=(char*)d_ws;
  size_t o=0;
  u16* tproj=(u16*)(ws+o); o+=32768;
  u16* tfc1 =(u16*)(ws+o); o+=131072;
  u16* tfc2 =(u16*)(ws+o); o+=131072;
  u16* aout =(u16*)(ws+o); o+=3211264;
  u16* qb   =(u16*)(ws+o); o+=3211264;
  u16* kb   =(u16*)(ws+o); o+=3211264;
  u16* vb   =(u16*)(ws+o); o+=3211264;

  qkv_ln_kernel<<<392,256,0,stream>>>(x,ln1w,ln1b,wqkv,bqkv,qb,kb,vb);
  attn_kernel<<<dim3(49,16),256,0,stream>>>(qb,kb,vb,rpb,wproj,wfc1,wfc2,
                                            tproj,tfc1,tfc2,aout);
  mega_mlp_kernel<<<196,512,0,stream>>>(aout,x,tproj,bproj,ln2w,ln2b,
                                        tfc1,bfc1,tfc2,bfc2,(float*)d_out);
}